// Round 2
// baseline (563.012 us; speedup 1.0000x reference)
//
#include <hip/hip_runtime.h>

// Problem constants
#define RED    100000   // reduction dim = C*RF*L = 1*50*2000
#define TT     32       // timesteps (M)
#define KF     512      // features (N)
#define THRESH 10.0f
#define KWTA   16

// GEMM tiling
#define CHUNKS 125      // red-dim split
#define CHUNK  800      // 125*800 = 100000
#define RB     32       // red elems per LDS stage
#define NSTAGE 25       // CHUNK/RB
#define TNK    64       // k-tile width
#define NKT    8        // KF/TNK
#define KK     2        // k-columns per thread

// ---------------------------------------------------------------------------
// K1: split-K GEMM, M-in-registers layout. Thread = (kg 0..31, slot 0..7).
// acc[32][2]: all 32 timesteps for 2 k-columns. A staged in LDS (4 KB),
// B streamed global->register (never LDS). Per stage: 32 ds_read_b128 +
// 2 global b128 per 256 FMAs.
// ---------------------------------------------------------------------------
template <int ATOMIC>
__global__ __launch_bounds__(256, 4)
void gemm_k(const float* __restrict__ rec, const float* __restrict__ wgt,
            float* __restrict__ dst) {
  __shared__ float Al[TT][RB];   // 4 KB, A tile [t][r]

  const int chunk = blockIdx.x;  // 0..124
  const int kt    = blockIdx.y;  // 0..7
  const int tid   = threadIdx.x;
  const int kg    = tid >> 3;    // 0..31  (also A-staging row)
  const int slot  = tid & 7;     // 0..7   (4-float red slot)

  const float* ap = rec + (size_t)kg * RED + chunk * CHUNK + slot * 4;
  const float* bp = wgt + (size_t)(kt * TNK + kg) * RED + chunk * CHUNK + slot * 4;
  const size_t bstride = (size_t)32 * RED;   // k -> k+32

  float acc[TT][KK];
#pragma unroll
  for (int t = 0; t < TT; ++t) { acc[t][0] = 0.f; acc[t][1] = 0.f; }

  // stage-0 prefetch
  float4 av = *(const float4*)ap;
  float4 b0 = *(const float4*)bp;
  float4 b1 = *(const float4*)(bp + bstride);

  for (int s = 0; s < NSTAGE; ++s) {
    __syncthreads();                    // previous compute done with LDS
    *(float4*)&Al[kg][slot * 4] = av;
    __syncthreads();
    const float4 cb0 = b0, cb1 = b1;
    if (s + 1 < NSTAGE) {               // issue next-stage loads early
      ap += RB; bp += RB;
      av = *(const float4*)ap;
      b0 = *(const float4*)bp;
      b1 = *(const float4*)(bp + bstride);
    }
#pragma unroll
    for (int t = 0; t < TT; ++t) {
      const float4 a = *(const float4*)&Al[t][slot * 4];  // 8-way broadcast
      acc[t][0] = fmaf(a.x, cb0.x, acc[t][0]);
      acc[t][0] = fmaf(a.y, cb0.y, acc[t][0]);
      acc[t][0] = fmaf(a.z, cb0.z, acc[t][0]);
      acc[t][0] = fmaf(a.w, cb0.w, acc[t][0]);
      acc[t][1] = fmaf(a.x, cb1.x, acc[t][1]);
      acc[t][1] = fmaf(a.y, cb1.y, acc[t][1]);
      acc[t][1] = fmaf(a.z, cb1.z, acc[t][1]);
      acc[t][1] = fmaf(a.w, cb1.w, acc[t][1]);
    }
  }

  // butterfly-reduce the 8 red-slots (lane bits 0..2)
#pragma unroll
  for (int m = 1; m <= 4; m <<= 1) {
#pragma unroll
    for (int t = 0; t < TT; ++t) {
      acc[t][0] += __shfl_xor(acc[t][0], m, 64);
      acc[t][1] += __shfl_xor(acc[t][1], m, 64);
    }
  }

  if (ATOMIC) {
#pragma unroll
    for (int j = 0; j < 4; ++j) {
      const int t = slot * 4 + j;
      atomicAdd(&dst[t * KF + kt * TNK + kg     ], acc[t][0]);
      atomicAdd(&dst[t * KF + kt * TNK + kg + 32], acc[t][1]);
    }
  } else {
    float* p = dst + (size_t)(chunk * NKT + kt) * TT * TNK;
#pragma unroll
    for (int j = 0; j < 4; ++j) {
      const int t = slot * 4 + j;       // each (t,kg) written exactly once
      p[t * TNK + kg     ] = acc[t][0];
      p[t * TNK + kg + 32] = acc[t][1];
    }
  }
}

// ---------------------------------------------------------------------------
// K2: reduce 125 partial tiles -> om[32][512]; layout [chunk][kt][t][kk]
// ---------------------------------------------------------------------------
__global__ __launch_bounds__(256)
void reduce_k(const float* __restrict__ part, float* __restrict__ om) {
  const int i  = blockIdx.x * 256 + threadIdx.x;  // 0..16383
  const int t  = i >> 9;
  const int k  = i & 511;
  const int kt = k >> 6;
  const int kk = k & 63;
  const float* p = part + (size_t)kt * TT * TNK + (size_t)t * TNK + kk;
  float s = 0.f;
#pragma unroll 5
  for (int c = 0; c < CHUNKS; ++c) s += p[(size_t)c * NKT * TT * TNK];
  om[i] = s;
}

// ---------------------------------------------------------------------------
// K3: threshold / nspk / first-spike value / v / total / 16x KWTA argmax
// (wave shfl_xor reductions, lowest-index tie-break) / final sign mask.
// om aliases d_out (fully overwritten, read-before-write per element).
// ---------------------------------------------------------------------------
__global__ __launch_bounds__(512)
void kwta_k(const float* __restrict__ om, float* __restrict__ out) {
  __shared__ float tot[KF];
  __shared__ float coef[KF];
  __shared__ float wmax[8];
  __shared__ int   widx[8];
  __shared__ float bflag;
  const int k    = threadIdx.x;   // feature
  const int lane = k & 63;
  const int wv   = k >> 6;

  int ns = 0;
#pragma unroll
  for (int t = 0; t < TT; ++t) ns += (om[t * KF + k] > THRESH) ? 1 : 0;
  int first = TT - ns;
  if (first > TT - 1) first = TT - 1;
  float pf = om[first * KF + k];
  pf = (pf > THRESH) ? pf : 0.0f;

  // v = max_k(values * sign(nspk)) * T
  float m = (ns > 0) ? pf : 0.0f;
#pragma unroll
  for (int off = 1; off <= 32; off <<= 1) m = fmaxf(m, __shfl_xor(m, off, 64));
  if (lane == 0) wmax[wv] = m;
  __syncthreads();
  float v = wmax[0];
#pragma unroll
  for (int w = 1; w < 8; ++w) v = fmaxf(v, wmax[w]);
  v *= (float)TT;

  const float t1 = (float)ns * pf;
  const float t2 = (float)ns * v;
  tot[k]  = t1 + t2;                   // >= 0 always
  coef[k] = 0.0f;
  __syncthreads();

  for (int it = 0; it < KWTA; ++it) {
    float val = tot[k];
    int   idx = k;
#pragma unroll
    for (int off = 1; off <= 32; off <<= 1) {
      const float ov = __shfl_xor(val, off, 64);
      const int   oi = __shfl_xor(idx, off, 64);
      if (ov > val || (ov == val && oi < idx)) { val = ov; idx = oi; }
    }
    if (lane == 0) { wmax[wv] = val; widx[wv] = idx; }
    __syncthreads();
    if (k == 0) {
      float bv = wmax[0]; int bi = widx[0];
#pragma unroll
      for (int w = 1; w < 8; ++w)
        if (wmax[w] > bv || (wmax[w] == bv && widx[w] < bi)) { bv = wmax[w]; bi = widx[w]; }
      if (bv != 0.0f) { tot[bi] = 0.0f; coef[bi] = 1.0f; bflag = 1.0f; }
      else            { bflag = 0.0f; }
    }
    __syncthreads();
    if (bflag == 0.0f) break;          // uniform: remaining winners = -1
  }
  __syncthreads();

  // out = sign(pot * coef); each element read-then-written by its own thread
  for (int i = k; i < TT * KF; i += KF) {
    const int kk = i & 511;
    const float p = om[i];
    out[i] = (p > THRESH && coef[kk] != 0.0f) ? 1.0f : 0.0f;
  }
}

// ---------------------------------------------------------------------------
extern "C" void kernel_launch(void* const* d_in, const int* in_sizes, int n_in,
                              void* d_out, int out_size, void* d_ws, size_t ws_size,
                              hipStream_t stream) {
  const float* rec = (const float*)d_in[0];   // (32,1,50,2000)
  const float* wgt = (const float*)d_in[1];   // (512,1,50,2000)
  float* out = (float*)d_out;                 // 16384 floats
  float* om  = (float*)d_out;                 // out-matrix aliases d_out
  const size_t part_bytes = (size_t)CHUNKS * NKT * TT * TNK * sizeof(float); // 8.192 MB

  if (ws_size >= part_bytes) {
    float* part = (float*)d_ws;
    gemm_k<0><<<dim3(CHUNKS, NKT), 256, 0, stream>>>(rec, wgt, part);
    reduce_k<<<(TT * KF) / 256, 256, 0, stream>>>(part, om);
  } else {
    hipMemsetAsync(om, 0, (size_t)TT * KF * sizeof(float), stream);
    gemm_k<1><<<dim3(CHUNKS, NKT), 256, 0, stream>>>(rec, wgt, om);
  }
  kwta_k<<<1, 512, 0, stream>>>(om, out);
}

// Round 3
// 557.354 us; speedup vs baseline: 1.0102x; 1.0102x over previous
//
#include <hip/hip_runtime.h>

// Problem constants
#define RED    100000   // reduction dim = C*RF*L = 1*50*2000
#define TT     32       // timesteps (M)
#define KF     512      // features (N)
#define THRESH 10.0f
#define KWTA   16

// GEMM tiling
#define CHUNKS 125      // red-dim split
#define CHUNK  800      // 125*800 = 100000
#define RB     32       // red elems per LDS stage
#define NSTAGE 25       // CHUNK/RB
#define TNK    64       // k-tile width
#define NKT    8        // KF/TNK
#define KK     2        // k-columns per thread

// ---------------------------------------------------------------------------
// K1: split-K GEMM, M-in-registers layout. Thread = (kg 0..31, slot 0..7).
// acc[32][2]: all 32 timesteps for 2 k-columns. A staged in LDS (4 KB),
// B streamed global->register (never LDS). Per stage: 32 ds_read_b128 +
// 2 global b128 per 256 FMAs.
// NOTE: launch_bounds min-waves=2 (VGPR cap 256). min-waves=4 capped at 128
// VGPRs and spilled acc to scratch (R2: VGPR_Count=48, WRITE_SIZE=1.39GB).
// ---------------------------------------------------------------------------
template <int ATOMIC>
__global__ __launch_bounds__(256, 2)
void gemm_k(const float* __restrict__ rec, const float* __restrict__ wgt,
            float* __restrict__ dst) {
  __shared__ float Al[TT][RB];   // 4 KB, A tile [t][r]

  const int chunk = blockIdx.x;  // 0..124
  const int kt    = blockIdx.y;  // 0..7
  const int tid   = threadIdx.x;
  const int kg    = tid >> 3;    // 0..31  (also A-staging row)
  const int slot  = tid & 7;     // 0..7   (4-float red slot)

  const float* ap = rec + (size_t)kg * RED + chunk * CHUNK + slot * 4;
  const float* bp = wgt + (size_t)(kt * TNK + kg) * RED + chunk * CHUNK + slot * 4;
  const size_t bstride = (size_t)32 * RED;   // k -> k+32

  float acc[TT][KK];
#pragma unroll
  for (int t = 0; t < TT; ++t) { acc[t][0] = 0.f; acc[t][1] = 0.f; }

  // stage-0 prefetch
  float4 av = *(const float4*)ap;
  float4 b0 = *(const float4*)bp;
  float4 b1 = *(const float4*)(bp + bstride);

#pragma unroll 1
  for (int s = 0; s < NSTAGE; ++s) {
    __syncthreads();                    // previous compute done with LDS
    *(float4*)&Al[kg][slot * 4] = av;
    __syncthreads();
    const float4 cb0 = b0, cb1 = b1;
    if (s + 1 < NSTAGE) {               // issue next-stage loads early
      ap += RB; bp += RB;
      av = *(const float4*)ap;
      b0 = *(const float4*)bp;
      b1 = *(const float4*)(bp + bstride);
    }
#pragma unroll
    for (int t = 0; t < TT; ++t) {
      const float4 a = *(const float4*)&Al[t][slot * 4];  // 8-way broadcast
      acc[t][0] = fmaf(a.x, cb0.x, acc[t][0]);
      acc[t][0] = fmaf(a.y, cb0.y, acc[t][0]);
      acc[t][0] = fmaf(a.z, cb0.z, acc[t][0]);
      acc[t][0] = fmaf(a.w, cb0.w, acc[t][0]);
      acc[t][1] = fmaf(a.x, cb1.x, acc[t][1]);
      acc[t][1] = fmaf(a.y, cb1.y, acc[t][1]);
      acc[t][1] = fmaf(a.z, cb1.z, acc[t][1]);
      acc[t][1] = fmaf(a.w, cb1.w, acc[t][1]);
    }
  }

  // butterfly-reduce the 8 red-slots (lane bits 0..2)
#pragma unroll
  for (int m = 1; m <= 4; m <<= 1) {
#pragma unroll
    for (int t = 0; t < TT; ++t) {
      acc[t][0] += __shfl_xor(acc[t][0], m, 64);
      acc[t][1] += __shfl_xor(acc[t][1], m, 64);
    }
  }

  if (ATOMIC) {
#pragma unroll
    for (int j = 0; j < 4; ++j) {
      const int t = slot * 4 + j;
      atomicAdd(&dst[t * KF + kt * TNK + kg     ], acc[t][0]);
      atomicAdd(&dst[t * KF + kt * TNK + kg + 32], acc[t][1]);
    }
  } else {
    float* p = dst + (size_t)(chunk * NKT + kt) * TT * TNK;
#pragma unroll
    for (int j = 0; j < 4; ++j) {
      const int t = slot * 4 + j;       // each (t,kg) written exactly once
      p[t * TNK + kg     ] = acc[t][0];
      p[t * TNK + kg + 32] = acc[t][1];
    }
  }
}

// ---------------------------------------------------------------------------
// K2: reduce 125 partial tiles -> om[32][512]; layout [chunk][kt][t][kk]
// ---------------------------------------------------------------------------
__global__ __launch_bounds__(256)
void reduce_k(const float* __restrict__ part, float* __restrict__ om) {
  const int i  = blockIdx.x * 256 + threadIdx.x;  // 0..16383
  const int t  = i >> 9;
  const int k  = i & 511;
  const int kt = k >> 6;
  const int kk = k & 63;
  const float* p = part + (size_t)kt * TT * TNK + (size_t)t * TNK + kk;
  float s = 0.f;
#pragma unroll 5
  for (int c = 0; c < CHUNKS; ++c) s += p[(size_t)c * NKT * TT * TNK];
  om[i] = s;
}

// ---------------------------------------------------------------------------
// K3: threshold / nspk / first-spike value / v / total / 16x KWTA argmax
// (wave shfl_xor reductions, lowest-index tie-break) / final sign mask.
// om aliases d_out (fully overwritten, read-before-write per element).
// ---------------------------------------------------------------------------
__global__ __launch_bounds__(512)
void kwta_k(const float* __restrict__ om, float* __restrict__ out) {
  __shared__ float tot[KF];
  __shared__ float coef[KF];
  __shared__ float wmax[8];
  __shared__ int   widx[8];
  __shared__ float bflag;
  const int k    = threadIdx.x;   // feature
  const int lane = k & 63;
  const int wv   = k >> 6;

  int ns = 0;
#pragma unroll
  for (int t = 0; t < TT; ++t) ns += (om[t * KF + k] > THRESH) ? 1 : 0;
  int first = TT - ns;
  if (first > TT - 1) first = TT - 1;
  float pf = om[first * KF + k];
  pf = (pf > THRESH) ? pf : 0.0f;

  // v = max_k(values * sign(nspk)) * T
  float m = (ns > 0) ? pf : 0.0f;
#pragma unroll
  for (int off = 1; off <= 32; off <<= 1) m = fmaxf(m, __shfl_xor(m, off, 64));
  if (lane == 0) wmax[wv] = m;
  __syncthreads();
  float v = wmax[0];
#pragma unroll
  for (int w = 1; w < 8; ++w) v = fmaxf(v, wmax[w]);
  v *= (float)TT;

  const float t1 = (float)ns * pf;
  const float t2 = (float)ns * v;
  tot[k]  = t1 + t2;                   // >= 0 always
  coef[k] = 0.0f;
  __syncthreads();

  for (int it = 0; it < KWTA; ++it) {
    float val = tot[k];
    int   idx = k;
#pragma unroll
    for (int off = 1; off <= 32; off <<= 1) {
      const float ov = __shfl_xor(val, off, 64);
      const int   oi = __shfl_xor(idx, off, 64);
      if (ov > val || (ov == val && oi < idx)) { val = ov; idx = oi; }
    }
    if (lane == 0) { wmax[wv] = val; widx[wv] = idx; }
    __syncthreads();
    if (k == 0) {
      float bv = wmax[0]; int bi = widx[0];
#pragma unroll
      for (int w = 1; w < 8; ++w)
        if (wmax[w] > bv || (wmax[w] == bv && widx[w] < bi)) { bv = wmax[w]; bi = widx[w]; }
      if (bv != 0.0f) { tot[bi] = 0.0f; coef[bi] = 1.0f; bflag = 1.0f; }
      else            { bflag = 0.0f; }
    }
    __syncthreads();
    if (bflag == 0.0f) break;          // uniform: remaining winners = -1
  }
  __syncthreads();

  // out = sign(pot * coef); each element read-then-written by its own thread
  for (int i = k; i < TT * KF; i += KF) {
    const int kk = i & 511;
    const float p = om[i];
    out[i] = (p > THRESH && coef[kk] != 0.0f) ? 1.0f : 0.0f;
  }
}

// ---------------------------------------------------------------------------
extern "C" void kernel_launch(void* const* d_in, const int* in_sizes, int n_in,
                              void* d_out, int out_size, void* d_ws, size_t ws_size,
                              hipStream_t stream) {
  const float* rec = (const float*)d_in[0];   // (32,1,50,2000)
  const float* wgt = (const float*)d_in[1];   // (512,1,50,2000)
  float* out = (float*)d_out;                 // 16384 floats
  float* om  = (float*)d_out;                 // out-matrix aliases d_out
  const size_t part_bytes = (size_t)CHUNKS * NKT * TT * TNK * sizeof(float); // 8.192 MB

  if (ws_size >= part_bytes) {
    float* part = (float*)d_ws;
    gemm_k<0><<<dim3(CHUNKS, NKT), 256, 0, stream>>>(rec, wgt, part);
    reduce_k<<<(TT * KF) / 256, 256, 0, stream>>>(part, om);
  } else {
    hipMemsetAsync(om, 0, (size_t)TT * KF * sizeof(float), stream);
    gemm_k<1><<<dim3(CHUNKS, NKT), 256, 0, stream>>>(rec, wgt, om);
  }
  kwta_k<<<1, 512, 0, stream>>>(om, out);
}

// Round 4
// 343.470 us; speedup vs baseline: 1.6392x; 1.6227x over previous
//
#include <hip/hip_runtime.h>

// Problem constants
#define RED    100000   // reduction dim = C*RF*L = 1*50*2000
#define TT     32       // timesteps (M)
#define KF     512      // features (N)
#define THRESH 10.0f
#define KWTA   16

// GEMM tiling
#define CHUNKS 125      // red-dim split
#define CHUNK  800      // 125*800 = 100000
#define RB     32       // red elems per LDS stage
#define NSTAGE 25       // CHUNK/RB
#define TNK    64       // k-tile width
#define NKT    8        // KF/TNK
#define KK     2        // k-columns per thread

// ---------------------------------------------------------------------------
// K1: split-K GEMM, M-in-registers layout. Thread = (kg 0..31, slot 0..7).
// acc[32][2]: all 32 timesteps for 2 k-columns. A staged in LDS (4 KB),
// B streamed global->register (never LDS).
// CRITICAL: every acc[] index must be COMPILE-TIME. R2/R3 regression: the
// epilogue indexed acc[slot*4+j] (runtime slot) -> whole array allocated in
// scratch -> 1.25 GB WRITE_SIZE, 325 us. Epilogue now iterates t=0..31
// (compile-time) with an exec-mask predicate instead.
// ---------------------------------------------------------------------------
template <int ATOMIC>
__global__ __launch_bounds__(256, 2)
void gemm_k(const float* __restrict__ rec, const float* __restrict__ wgt,
            float* __restrict__ dst) {
  __shared__ float Al[TT][RB];   // 4 KB, A tile [t][r]

  const int chunk = blockIdx.x;  // 0..124
  const int kt    = blockIdx.y;  // 0..7
  const int tid   = threadIdx.x;
  const int kg    = tid >> 3;    // 0..31  (also A-staging row)
  const int slot  = tid & 7;     // 0..7   (4-float red slot)

  const float* ap = rec + (size_t)kg * RED + chunk * CHUNK + slot * 4;
  const float* bp = wgt + (size_t)(kt * TNK + kg) * RED + chunk * CHUNK + slot * 4;
  const size_t bstride = (size_t)32 * RED;   // k -> k+32

  float acc[TT][KK];
#pragma unroll
  for (int t = 0; t < TT; ++t) { acc[t][0] = 0.f; acc[t][1] = 0.f; }

  // stage-0 prefetch
  float4 av = *(const float4*)ap;
  float4 b0 = *(const float4*)bp;
  float4 b1 = *(const float4*)(bp + bstride);

#pragma unroll 1
  for (int s = 0; s < NSTAGE; ++s) {
    __syncthreads();                    // previous compute done with LDS
    *(float4*)&Al[kg][slot * 4] = av;
    __syncthreads();
    const float4 cb0 = b0, cb1 = b1;
    if (s + 1 < NSTAGE) {               // issue next-stage loads early
      ap += RB; bp += RB;
      av = *(const float4*)ap;
      b0 = *(const float4*)bp;
      b1 = *(const float4*)(bp + bstride);
    }
#pragma unroll
    for (int t = 0; t < TT; ++t) {
      const float4 a = *(const float4*)&Al[t][slot * 4];  // 8-way broadcast
      acc[t][0] = fmaf(a.x, cb0.x, acc[t][0]);
      acc[t][0] = fmaf(a.y, cb0.y, acc[t][0]);
      acc[t][0] = fmaf(a.z, cb0.z, acc[t][0]);
      acc[t][0] = fmaf(a.w, cb0.w, acc[t][0]);
      acc[t][1] = fmaf(a.x, cb1.x, acc[t][1]);
      acc[t][1] = fmaf(a.y, cb1.y, acc[t][1]);
      acc[t][1] = fmaf(a.z, cb1.z, acc[t][1]);
      acc[t][1] = fmaf(a.w, cb1.w, acc[t][1]);
    }
  }

  // butterfly-reduce the 8 red-slots (lane bits 0..2); all indices static
#pragma unroll
  for (int m = 1; m <= 4; m <<= 1) {
#pragma unroll
    for (int t = 0; t < TT; ++t) {
      acc[t][0] += __shfl_xor(acc[t][0], m, 64);
      acc[t][1] += __shfl_xor(acc[t][1], m, 64);
    }
  }

  // epilogue: one writer per (t,kg) = the lane with slot == t>>2.
  // acc index is the compile-time t; predicate only masks exec.
  if (ATOMIC) {
#pragma unroll
    for (int t = 0; t < TT; ++t) {
      if (slot == (t >> 2)) {
        atomicAdd(&dst[t * KF + kt * TNK + kg     ], acc[t][0]);
        atomicAdd(&dst[t * KF + kt * TNK + kg + 32], acc[t][1]);
      }
    }
  } else {
    float* p = dst + (size_t)(chunk * NKT + kt) * TT * TNK;
#pragma unroll
    for (int t = 0; t < TT; ++t) {
      if (slot == (t >> 2)) {
        p[t * TNK + kg     ] = acc[t][0];
        p[t * TNK + kg + 32] = acc[t][1];
      }
    }
  }
}

// ---------------------------------------------------------------------------
// K2: reduce 125 partial tiles -> om[32][512]; layout [chunk][kt][t][kk]
// ---------------------------------------------------------------------------
__global__ __launch_bounds__(256)
void reduce_k(const float* __restrict__ part, float* __restrict__ om) {
  const int i  = blockIdx.x * 256 + threadIdx.x;  // 0..16383
  const int t  = i >> 9;
  const int k  = i & 511;
  const int kt = k >> 6;
  const int kk = k & 63;
  const float* p = part + (size_t)kt * TT * TNK + (size_t)t * TNK + kk;
  float s = 0.f;
#pragma unroll 5
  for (int c = 0; c < CHUNKS; ++c) s += p[(size_t)c * NKT * TT * TNK];
  om[i] = s;
}

// ---------------------------------------------------------------------------
// K3: threshold / nspk / first-spike value / v / total / 16x KWTA argmax
// (wave shfl_xor reductions, lowest-index tie-break) / final sign mask.
// om aliases d_out (fully overwritten, read-before-write per element).
// ---------------------------------------------------------------------------
__global__ __launch_bounds__(512)
void kwta_k(const float* __restrict__ om, float* __restrict__ out) {
  __shared__ float tot[KF];
  __shared__ float coef[KF];
  __shared__ float wmax[8];
  __shared__ int   widx[8];
  __shared__ float bflag;
  const int k    = threadIdx.x;   // feature
  const int lane = k & 63;
  const int wv   = k >> 6;

  int ns = 0;
#pragma unroll
  for (int t = 0; t < TT; ++t) ns += (om[t * KF + k] > THRESH) ? 1 : 0;
  int first = TT - ns;
  if (first > TT - 1) first = TT - 1;
  float pf = om[first * KF + k];
  pf = (pf > THRESH) ? pf : 0.0f;

  // v = max_k(values * sign(nspk)) * T
  float m = (ns > 0) ? pf : 0.0f;
#pragma unroll
  for (int off = 1; off <= 32; off <<= 1) m = fmaxf(m, __shfl_xor(m, off, 64));
  if (lane == 0) wmax[wv] = m;
  __syncthreads();
  float v = wmax[0];
#pragma unroll
  for (int w = 1; w < 8; ++w) v = fmaxf(v, wmax[w]);
  v *= (float)TT;

  const float t1 = (float)ns * pf;
  const float t2 = (float)ns * v;
  tot[k]  = t1 + t2;                   // >= 0 always
  coef[k] = 0.0f;
  __syncthreads();

  for (int it = 0; it < KWTA; ++it) {
    float val = tot[k];
    int   idx = k;
#pragma unroll
    for (int off = 1; off <= 32; off <<= 1) {
      const float ov = __shfl_xor(val, off, 64);
      const int   oi = __shfl_xor(idx, off, 64);
      if (ov > val || (ov == val && oi < idx)) { val = ov; idx = oi; }
    }
    if (lane == 0) { wmax[wv] = val; widx[wv] = idx; }
    __syncthreads();
    if (k == 0) {
      float bv = wmax[0]; int bi = widx[0];
#pragma unroll
      for (int w = 1; w < 8; ++w)
        if (wmax[w] > bv || (wmax[w] == bv && widx[w] < bi)) { bv = wmax[w]; bi = widx[w]; }
      if (bv != 0.0f) { tot[bi] = 0.0f; coef[bi] = 1.0f; bflag = 1.0f; }
      else            { bflag = 0.0f; }
    }
    __syncthreads();
    if (bflag == 0.0f) break;          // uniform: remaining winners = -1
  }
  __syncthreads();

  // out = sign(pot * coef); each element read-then-written by its own thread
  for (int i = k; i < TT * KF; i += KF) {
    const int kk = i & 511;
    const float p = om[i];
    out[i] = (p > THRESH && coef[kk] != 0.0f) ? 1.0f : 0.0f;
  }
}

// ---------------------------------------------------------------------------
extern "C" void kernel_launch(void* const* d_in, const int* in_sizes, int n_in,
                              void* d_out, int out_size, void* d_ws, size_t ws_size,
                              hipStream_t stream) {
  const float* rec = (const float*)d_in[0];   // (32,1,50,2000)
  const float* wgt = (const float*)d_in[1];   // (512,1,50,2000)
  float* out = (float*)d_out;                 // 16384 floats
  float* om  = (float*)d_out;                 // out-matrix aliases d_out
  const size_t part_bytes = (size_t)CHUNKS * NKT * TT * TNK * sizeof(float); // 8.192 MB

  if (ws_size >= part_bytes) {
    float* part = (float*)d_ws;
    gemm_k<0><<<dim3(CHUNKS, NKT), 256, 0, stream>>>(rec, wgt, part);
    reduce_k<<<(TT * KF) / 256, 256, 0, stream>>>(part, om);
  } else {
    hipMemsetAsync(om, 0, (size_t)TT * KF * sizeof(float), stream);
    gemm_k<1><<<dim3(CHUNKS, NKT), 256, 0, stream>>>(rec, wgt, om);
  }
  kwta_k<<<1, 512, 0, stream>>>(om, out);
}